// Round 2
// baseline (873.215 us; speedup 1.0000x reference)
//
#include <hip/hip_runtime.h>
#include <cstdint>
#include <cstddef>

#define B_ 64
#define N_ 4096
#define D_ 512
#define A_ 128

typedef unsigned short u16;
typedef __attribute__((ext_vector_type(8))) short bf16x8;   // 8 bf16 in 4 VGPRs
typedef __attribute__((ext_vector_type(4))) float f32x4;

__device__ __forceinline__ u16 cvt_bf16(float x) {
    unsigned u = __float_as_uint(x);
    return (u16)((u + 0x7FFFu + ((u >> 16) & 1u)) >> 16);   // RNE
}
__device__ __forceinline__ unsigned pack2_bf16(float a, float b) {
    unsigned ua = __float_as_uint(a), ub = __float_as_uint(b);
    unsigned ra = (ua + 0x7FFFu + ((ua >> 16) & 1u)) >> 16;
    unsigned rb = (ub + 0x7FFFu + ((ub >> 16) & 1u)) >> 16;
    return ra | (rb << 16);
}
__device__ __forceinline__ float fast_tanh(float x) {
    float ax = fabsf(x);
    float e  = __expf(-2.0f * ax);
    float r  = __fdividef(1.0f - e, 1.0f + e);
    return x < 0.0f ? -r : r;
}

// ---------------------------------------------------------------- kernel 0
// blocks 0..63 : W_I [D][A] fp32 -> Wbf [A][K=D] bf16 (transposed)
// blocks 64..127: q_att[b][:] = tanh(v_Q@W_Q + b_Q); u[b][:] = v_Q[b][:]; sums[b]=0
__global__ void k_prep(const float* __restrict__ WI, const float* __restrict__ vQ,
                       const float* __restrict__ WQ, const float* __restrict__ bQ,
                       u16* __restrict__ Wbf, float* __restrict__ qatt,
                       float* __restrict__ sums, float* __restrict__ u) {
    const int blk = blockIdx.x, t = threadIdx.x;   // 128 threads
    if (blk < 64) {
        #pragma unroll
        for (int i = 0; i < 2; ++i) {
            int item = blk * 256 + i * 128 + t;    // 16384 items
            int a  = item & 127;
            int d0 = (item >> 7) << 2;
            ushort4 r;
            r.x = cvt_bf16(WI[(d0 + 0) * A_ + a]);
            r.y = cvt_bf16(WI[(d0 + 1) * A_ + a]);
            r.z = cvt_bf16(WI[(d0 + 2) * A_ + a]);
            r.w = cvt_bf16(WI[(d0 + 3) * A_ + a]);
            *(ushort4*)&Wbf[a * D_ + d0] = r;
        }
    } else {
        const int b = blk - 64;
        __shared__ float sq[D_];
        for (int d = t; d < D_; d += 128) sq[d] = vQ[b * D_ + d];
        __syncthreads();
        float acc = bQ[t];
        #pragma unroll 8
        for (int d = 0; d < D_; ++d) acc += sq[d] * WQ[d * A_ + t];
        qatt[b * A_ + t] = fast_tanh(acc);
        // u := v_Q  (k_wsum accumulates on top)
        float4 vq4 = *(const float4*)(vQ + b * D_ + t * 4);
        *(float4*)(u + b * D_ + t * 4) = vq4;
        if (t == 0) sums[b] = 0.0f;
    }
}

// ---------------------------------------------------------------- kernel 1
// Barrier-free fused GEMM. Per block: rows [n0, n0+128) of batch b.
// Each wave owns 32 rows; A and B fragments loaded DIRECTLY from global in
// MFMA layout (no LDS, no __syncthreads in the K-loop).
// Emits w[b][n] = exp(logit) and per-block partial sum into sums[b].
__global__ void __launch_bounds__(256)
k_gemm(const float* __restrict__ vI, const u16* __restrict__ Wbf,
       const float* __restrict__ qatt, const float* __restrict__ Wp,
       float* __restrict__ w_out, float* __restrict__ sums) {
    const int b  = blockIdx.y;
    const int n0 = blockIdx.x * 128;
    const int t    = threadIdx.x;
    const int lane = t & 63, wave = t >> 6;
    const int l15  = lane & 15, quad = lane >> 4;

    f32x4 acc[2][8];
    #pragma unroll
    for (int mt = 0; mt < 2; ++mt)
        #pragma unroll
        for (int nt = 0; nt < 8; ++nt)
            acc[mt][nt] = (f32x4){0.f, 0.f, 0.f, 0.f};

    // A fragment pointers: row = n0 + wave*32 + mt*16 + l15, k-offset quad*8
    const float* a0p = vI + (size_t)(b * N_ + n0 + wave * 32 + l15) * D_ + quad * 8;
    const float* a1p = a0p + 16 * D_;
    // B fragment base: a-row = nt*16 + l15, k-offset quad*8 (bf16, k-contiguous)
    const u16* bbase = Wbf + (size_t)l15 * D_ + quad * 8;

    #pragma unroll 2
    for (int kk = 0; kk < 16; ++kk) {           // K = 512, 32 per step
        const int ko = kk * 32;
        float4 a0a = *(const float4*)(a0p + ko);
        float4 a0b = *(const float4*)(a0p + ko + 4);
        float4 a1a = *(const float4*)(a1p + ko);
        float4 a1b = *(const float4*)(a1p + ko + 4);
        bf16x8 bfr[8];
        #pragma unroll
        for (int nt = 0; nt < 8; ++nt)
            bfr[nt] = *(const bf16x8*)(bbase + nt * 16 * D_ + ko);
        union { bf16x8 v; unsigned u[4]; } c0, c1;
        c0.u[0] = pack2_bf16(a0a.x, a0a.y);
        c0.u[1] = pack2_bf16(a0a.z, a0a.w);
        c0.u[2] = pack2_bf16(a0b.x, a0b.y);
        c0.u[3] = pack2_bf16(a0b.z, a0b.w);
        c1.u[0] = pack2_bf16(a1a.x, a1a.y);
        c1.u[1] = pack2_bf16(a1a.z, a1a.w);
        c1.u[2] = pack2_bf16(a1b.x, a1b.y);
        c1.u[3] = pack2_bf16(a1b.z, a1b.w);
        bf16x8 af[2] = { c0.v, c1.v };
        #pragma unroll
        for (int mt = 0; mt < 2; ++mt)
            #pragma unroll
            for (int nt = 0; nt < 8; ++nt)
                acc[mt][nt] = __builtin_amdgcn_mfma_f32_16x16x32_bf16(
                    af[mt], bfr[nt], acc[mt][nt], 0, 0, 0);
    }

    // epilogue: C/D layout col(a) = lane&15, row = quad*4 + reg
    float qa_v[8], wp_v[8];
    #pragma unroll
    for (int nt = 0; nt < 8; ++nt) {
        int a = nt * 16 + l15;
        qa_v[nt] = qatt[b * A_ + a];
        wp_v[nt] = Wp[a];
    }
    float lsum = 0.f;
    #pragma unroll
    for (int mt = 0; mt < 2; ++mt) {
        #pragma unroll
        for (int r = 0; r < 4; ++r) {
            float s = 0.f;
            #pragma unroll
            for (int nt = 0; nt < 8; ++nt) {
                float t1 = fast_tanh(acc[mt][nt][r]);
                float h  = fast_tanh(t1 + qa_v[nt]);
                s += h * wp_v[nt];
            }
            s += __shfl_xor(s, 1, 16);
            s += __shfl_xor(s, 2, 16);
            s += __shfl_xor(s, 4, 16);
            s += __shfl_xor(s, 8, 16);
            // |s| <= sum|W_p| ~ 9 -> exp safe in fp32, softmax needs no max-sub
            float we = __expf(s);
            lsum += we;                          // same value on all 16 lanes of group
            if (l15 == 0)
                w_out[(size_t)b * N_ + n0 + wave * 32 + mt * 16 + quad * 4 + r] = we;
        }
    }
    // lsum identical across l15 within a quad-group; sum across quads = wave total
    lsum += __shfl_xor(lsum, 16, 64);
    lsum += __shfl_xor(lsum, 32, 64);
    __shared__ float wred[4];
    if (lane == 0) wred[wave] = lsum;
    __syncthreads();
    if (t == 0) atomicAdd(sums + b, wred[0] + wred[1] + wred[2] + wred[3]);
}

// ---------------------------------------------------------------- kernel 2
// p[b][n] = w[b][n]/S_b (written to d_out);  u[b][d] += sum_n p * v_I[b][n][d]
__global__ void __launch_bounds__(256)
k_wsum(const float* __restrict__ vI, const float* __restrict__ w,
       const float* __restrict__ sums, float* __restrict__ p_out,
       float* __restrict__ u) {
    const int b  = blockIdx.y;
    const int n0 = blockIdx.x * 256;
    const int t  = threadIdx.x;
    const float inv = 1.0f / sums[b];
    __shared__ float sp[256];
    float pv = w[(size_t)b * N_ + n0 + t] * inv;
    sp[t] = pv;
    p_out[(size_t)b * N_ + n0 + t] = pv;
    __syncthreads();
    const int rr = t >> 7;            // 0..1: two rows in flight
    const int c  = t & 127;           // float4 column
    const float4* base = (const float4*)(vI + (size_t)(b * N_ + n0 + rr) * D_) + c;
    float a0 = 0.f, a1 = 0.f, a2 = 0.f, a3 = 0.f;
    #pragma unroll 8
    for (int n = 0; n < 256; n += 2) {
        float4 x = base[n * 128];
        float wn = sp[n + rr];
        a0 += wn * x.x; a1 += wn * x.y; a2 += wn * x.z; a3 += wn * x.w;
    }
    float* ub = u + b * D_ + c * 4;
    atomicAdd(ub + 0, a0);
    atomicAdd(ub + 1, a1);
    atomicAdd(ub + 2, a2);
    atomicAdd(ub + 3, a3);
}

// ----------------------------------------------------------------
extern "C" void kernel_launch(void* const* d_in, const int* in_sizes, int n_in,
                              void* d_out, int out_size, void* d_ws, size_t ws_size,
                              hipStream_t stream) {
    const float* vI = (const float*)d_in[0];
    const float* vQ = (const float*)d_in[1];
    const float* WI = (const float*)d_in[2];
    const float* WQ = (const float*)d_in[3];
    const float* bQ = (const float*)d_in[4];
    const float* Wp = (const float*)d_in[5];
    // d_in[6] (b_p): constant added to all logits -> cancels in softmax.

    float* out_p = (float*)d_out;                    // [B][N]
    float* out_u = out_p + (size_t)B_ * N_;          // [B][D]

    char* ws = (char*)d_ws;
    u16*   Wbf  = (u16*)ws;                              // 128 KiB
    float* qatt = (float*)(ws + 131072);                 // 32 KiB
    float* sums = (float*)(ws + 131072 + 32768);         // 256 B
    float* wbuf = (float*)(ws + 131072 + 32768 + 1024);  // [B][N] 1 MiB

    k_prep<<<128, 128, 0, stream>>>(WI, vQ, WQ, bQ, Wbf, qatt, sums, out_u);
    k_gemm<<<dim3(N_ / 128, B_), 256, 0, stream>>>(vI, Wbf, qatt, Wp, wbuf, sums);
    k_wsum<<<dim3(N_ / 256, B_), 256, 0, stream>>>(vI, wbuf, sums, out_p, out_u);
}

// Round 3
// 833.629 us; speedup vs baseline: 1.0475x; 1.0475x over previous
//
#include <hip/hip_runtime.h>
#include <cstdint>
#include <cstddef>

#define B_ 64
#define N_ 4096
#define D_ 512
#define A_ 128

typedef unsigned short u16;
typedef __attribute__((ext_vector_type(8))) short bf16x8;   // 8 bf16 in 4 VGPRs
typedef __attribute__((ext_vector_type(4))) float f32x4;

__device__ __forceinline__ u16 cvt_bf16(float x) {
    unsigned u = __float_as_uint(x);
    return (u16)((u + 0x7FFFu + ((u >> 16) & 1u)) >> 16);   // RNE
}
__device__ __forceinline__ unsigned pack2_bf16(float a, float b) {
    unsigned ua = __float_as_uint(a), ub = __float_as_uint(b);
    unsigned ra = (ua + 0x7FFFu + ((ua >> 16) & 1u)) >> 16;
    unsigned rb = (ub + 0x7FFFu + ((ub >> 16) & 1u)) >> 16;
    return ra | (rb << 16);
}
__device__ __forceinline__ float fast_tanh(float x) {
    float ax = fabsf(x);
    float e  = __expf(-2.0f * ax);
    float r  = __fdividef(1.0f - e, 1.0f + e);
    return x < 0.0f ? -r : r;
}

// ---------------------------------------------------------------- kernel 0
// blocks 0..63  : W_I [D][A] fp32 -> Wbf [A][K=D] bf16 (transposed)
// blocks 64..127: q_att[b] = tanh(v_Q@W_Q + b_Q); zero sums[b], u_raw[b][:]
__global__ void k_prep(const float* __restrict__ WI, const float* __restrict__ vQ,
                       const float* __restrict__ WQ, const float* __restrict__ bQ,
                       u16* __restrict__ Wbf, float* __restrict__ qatt,
                       float* __restrict__ sums, float* __restrict__ u_raw) {
    const int blk = blockIdx.x, t = threadIdx.x;   // 128 threads
    if (blk < 64) {
        #pragma unroll
        for (int i = 0; i < 2; ++i) {
            int item = blk * 256 + i * 128 + t;    // 16384 items
            int a  = item & 127;
            int d0 = (item >> 7) << 2;
            ushort4 r;
            r.x = cvt_bf16(WI[(d0 + 0) * A_ + a]);
            r.y = cvt_bf16(WI[(d0 + 1) * A_ + a]);
            r.z = cvt_bf16(WI[(d0 + 2) * A_ + a]);
            r.w = cvt_bf16(WI[(d0 + 3) * A_ + a]);
            *(ushort4*)&Wbf[a * D_ + d0] = r;
        }
    } else {
        const int b = blk - 64;
        __shared__ float sq[D_];
        for (int d = t; d < D_; d += 128) sq[d] = vQ[b * D_ + d];
        __syncthreads();
        float acc = bQ[t];
        #pragma unroll 8
        for (int d = 0; d < D_; ++d) acc += sq[d] * WQ[d * A_ + t];
        qatt[b * A_ + t] = fast_tanh(acc);
        float4 z = {0.f, 0.f, 0.f, 0.f};
        *(float4*)(u_raw + b * D_ + t * 4) = z;
        if (t == 0) sums[b] = 0.0f;
    }
}

// ---------------------------------------------------------------- kernel 1
// Fused: per block = 128 rows of batch b.
//  phase 1: logits via direct-from-global MFMA GEMM (no LDS staging),
//           w = exp(logit) -> wbuf + LDS, partial sum -> sums[b] (atomic)
//  phase 2: re-read own 256 KB tile (L2/L3-hot) and accumulate
//           sum_n w_n * v_I[n][d] into u_raw[b][d] (fp32 atomics)
__global__ void __launch_bounds__(256)
k_fused(const float* __restrict__ vI, const u16* __restrict__ Wbf,
        const float* __restrict__ qatt, const float* __restrict__ Wp,
        float* __restrict__ wbuf, float* __restrict__ sums,
        float* __restrict__ u_raw) {
    const int b  = blockIdx.y;
    const int n0 = blockIdx.x * 128;
    const int t    = threadIdx.x;
    const int lane = t & 63, wave = t >> 6;
    const int l15  = lane & 15, quad = lane >> 4;

    __shared__ float sw[128];
    __shared__ float wred[4];

    f32x4 acc[2][8];
    #pragma unroll
    for (int mt = 0; mt < 2; ++mt)
        #pragma unroll
        for (int nt = 0; nt < 8; ++nt)
            acc[mt][nt] = (f32x4){0.f, 0.f, 0.f, 0.f};

    // A fragment pointers: row = n0 + wave*32 + mt*16 + l15, k-offset quad*8
    const float* a0p = vI + (size_t)(b * N_ + n0 + wave * 32 + l15) * D_ + quad * 8;
    const float* a1p = a0p + 16 * D_;
    // B fragment base: a-row = nt*16 + l15, k-offset quad*8 (bf16, k-contiguous)
    const u16* bbase = Wbf + (size_t)l15 * D_ + quad * 8;

    // 1-deep A prefetch pipeline, fully unrolled K-loop (K=512, 32/step)
    float4 c0a = *(const float4*)(a0p);
    float4 c0b = *(const float4*)(a0p + 4);
    float4 c1a = *(const float4*)(a1p);
    float4 c1b = *(const float4*)(a1p + 4);
    #pragma unroll
    for (int kk = 0; kk < 16; ++kk) {
        float4 n0a, n0b, n1a, n1b;
        if (kk < 15) {
            const int ko = (kk + 1) * 32;
            n0a = *(const float4*)(a0p + ko);
            n0b = *(const float4*)(a0p + ko + 4);
            n1a = *(const float4*)(a1p + ko);
            n1b = *(const float4*)(a1p + ko + 4);
        }
        bf16x8 bfr[8];
        #pragma unroll
        for (int nt = 0; nt < 8; ++nt)
            bfr[nt] = *(const bf16x8*)(bbase + nt * 16 * D_ + kk * 32);
        union { bf16x8 v; unsigned u[4]; } c0, c1;
        c0.u[0] = pack2_bf16(c0a.x, c0a.y);
        c0.u[1] = pack2_bf16(c0a.z, c0a.w);
        c0.u[2] = pack2_bf16(c0b.x, c0b.y);
        c0.u[3] = pack2_bf16(c0b.z, c0b.w);
        c1.u[0] = pack2_bf16(c1a.x, c1a.y);
        c1.u[1] = pack2_bf16(c1a.z, c1a.w);
        c1.u[2] = pack2_bf16(c1b.x, c1b.y);
        c1.u[3] = pack2_bf16(c1b.z, c1b.w);
        bf16x8 af[2] = { c0.v, c1.v };
        #pragma unroll
        for (int mt = 0; mt < 2; ++mt)
            #pragma unroll
            for (int nt = 0; nt < 8; ++nt)
                acc[mt][nt] = __builtin_amdgcn_mfma_f32_16x16x32_bf16(
                    af[mt], bfr[nt], acc[mt][nt], 0, 0, 0);
        c0a = n0a; c0b = n0b; c1a = n1a; c1b = n1b;
    }

    // epilogue: C/D layout col(a) = lane&15, row = quad*4 + reg
    float qa_v[8], wp_v[8];
    #pragma unroll
    for (int nt = 0; nt < 8; ++nt) {
        int a = nt * 16 + l15;
        qa_v[nt] = qatt[b * A_ + a];
        wp_v[nt] = Wp[a];
    }
    float lsum = 0.f;
    #pragma unroll
    for (int mt = 0; mt < 2; ++mt) {
        #pragma unroll
        for (int r = 0; r < 4; ++r) {
            float s = 0.f;
            #pragma unroll
            for (int nt = 0; nt < 8; ++nt) {
                float t1 = fast_tanh(acc[mt][nt][r]);
                float h  = fast_tanh(t1 + qa_v[nt]);
                s += h * wp_v[nt];
            }
            s += __shfl_xor(s, 1, 16);
            s += __shfl_xor(s, 2, 16);
            s += __shfl_xor(s, 4, 16);
            s += __shfl_xor(s, 8, 16);
            // |s| <= sum|W_p| ~ 9 -> exp safe in fp32; softmax needs no max-sub
            float we = __expf(s);
            lsum += we;                          // same value on all 16 lanes
            if (l15 == 0) {
                int rloc = wave * 32 + mt * 16 + quad * 4 + r;
                wbuf[(size_t)b * N_ + n0 + rloc] = we;
                sw[rloc] = we;
            }
        }
    }
    lsum += __shfl_xor(lsum, 16, 64);
    lsum += __shfl_xor(lsum, 32, 64);
    if (lane == 0) wred[wave] = lsum;
    __syncthreads();
    if (t == 0) atomicAdd(sums + b, wred[0] + wred[1] + wred[2] + wred[3]);

    // ---- phase 2: weighted sum of own tile (cache-hot re-read) ----
    const int rr = t >> 7;            // 0..1: two rows in flight
    const int c  = t & 127;           // float4 column
    const float4* base = (const float4*)(vI + (size_t)(b * N_ + n0 + rr) * D_) + c;
    float a0 = 0.f, a1 = 0.f, a2 = 0.f, a3 = 0.f;
    #pragma unroll 8
    for (int n = 0; n < 128; n += 2) {
        float4 x = base[n * 128];
        float wn = sw[n + rr];
        a0 += wn * x.x; a1 += wn * x.y; a2 += wn * x.z; a3 += wn * x.w;
    }
    float* ub = u_raw + b * D_ + c * 4;
    atomicAdd(ub + 0, a0);
    atomicAdd(ub + 1, a1);
    atomicAdd(ub + 2, a2);
    atomicAdd(ub + 3, a3);
}

// ---------------------------------------------------------------- kernel 2
// p[b][n] = w[b][n]/S_b ;  u[b][d] = u_raw[b][d]/S_b + v_Q[b][d]
__global__ void __launch_bounds__(256)
k_fin(const float* __restrict__ wbuf, const float* __restrict__ sums,
      const float* __restrict__ u_raw, const float* __restrict__ vQ,
      float* __restrict__ p_out, float* __restrict__ u_out) {
    const int b = blockIdx.x, t = threadIdx.x;    // 256 threads
    const float inv = 1.0f / sums[b];
    #pragma unroll
    for (int i = 0; i < 4; ++i) {
        float4 x = *(const float4*)(wbuf + (size_t)b * N_ + i * 1024 + t * 4);
        float4 y = { x.x * inv, x.y * inv, x.z * inv, x.w * inv };
        *(float4*)(p_out + (size_t)b * N_ + i * 1024 + t * 4) = y;
    }
    if (t < 128) {
        float4 ur = *(const float4*)(u_raw + b * D_ + t * 4);
        float4 vq = *(const float4*)(vQ + b * D_ + t * 4);
        float4 o  = { ur.x * inv + vq.x, ur.y * inv + vq.y,
                      ur.z * inv + vq.z, ur.w * inv + vq.w };
        *(float4*)(u_out + b * D_ + t * 4) = o;
    }
}

// ----------------------------------------------------------------
extern "C" void kernel_launch(void* const* d_in, const int* in_sizes, int n_in,
                              void* d_out, int out_size, void* d_ws, size_t ws_size,
                              hipStream_t stream) {
    const float* vI = (const float*)d_in[0];
    const float* vQ = (const float*)d_in[1];
    const float* WI = (const float*)d_in[2];
    const float* WQ = (const float*)d_in[3];
    const float* bQ = (const float*)d_in[4];
    const float* Wp = (const float*)d_in[5];
    // d_in[6] (b_p): constant added to all logits -> cancels in softmax.

    float* out_p = (float*)d_out;                    // [B][N]
    float* out_u = out_p + (size_t)B_ * N_;          // [B][D]

    char* ws = (char*)d_ws;
    u16*   Wbf   = (u16*)ws;                             // 128 KiB @ 0
    float* qatt  = (float*)(ws + 131072);                // 32 KiB
    float* sums  = (float*)(ws + 163840);                // 1 KiB
    float* u_raw = (float*)(ws + 164864);                // 128 KiB
    float* wbuf  = (float*)(ws + 295936);                // 1 MiB

    k_prep<<<128, 128, 0, stream>>>(WI, vQ, WQ, bQ, Wbf, qatt, sums, u_raw);
    k_fused<<<dim3(N_ / 128, B_), 256, 0, stream>>>(vI, Wbf, qatt, Wp,
                                                    wbuf, sums, u_raw);
    k_fin<<<B_, 256, 0, stream>>>(wbuf, sums, u_raw, vQ, out_p, out_u);
}

// Round 4
// 785.378 us; speedup vs baseline: 1.1118x; 1.0614x over previous
//
#include <hip/hip_runtime.h>
#include <cstdint>
#include <cstddef>

#define B_ 64
#define N_ 4096
#define D_ 512
#define A_ 128
#define BK 64

typedef unsigned short u16;
typedef __attribute__((ext_vector_type(8))) short bf16x8;   // 8 bf16 in 4 VGPRs
typedef __attribute__((ext_vector_type(4))) float f32x4;

__device__ __forceinline__ u16 cvt_bf16(float x) {
    unsigned u = __float_as_uint(x);
    return (u16)((u + 0x7FFFu + ((u >> 16) & 1u)) >> 16);   // RNE
}
__device__ __forceinline__ unsigned pack2_bf16(float a, float b) {
    unsigned ua = __float_as_uint(a), ub = __float_as_uint(b);
    unsigned ra = (ua + 0x7FFFu + ((ua >> 16) & 1u)) >> 16;
    unsigned rb = (ub + 0x7FFFu + ((ub >> 16) & 1u)) >> 16;
    return ra | (rb << 16);
}
__device__ __forceinline__ float fast_tanh(float x) {
    float ax = fabsf(x);
    float e  = __expf(-2.0f * ax);
    float r  = __fdividef(1.0f - e, 1.0f + e);
    return x < 0.0f ? -r : r;
}
// async global->LDS, 16 B per lane, LDS dest = wave-uniform base + lane*16
__device__ __forceinline__ void gl_lds16(const void* g, void* l) {
    __builtin_amdgcn_global_load_lds(
        (const __attribute__((address_space(1))) unsigned int*)g,
        (__attribute__((address_space(3))) unsigned int*)l, 16, 0, 0);
}

// ---------------------------------------------------------------- kernel 0
// blocks 0..63  : W_I [D][A] fp32 -> Wbf [A][K=D] bf16 (transposed)
// blocks 64..127: q_att[b] = tanh(v_Q@W_Q + b_Q); zero sums[b], u_raw[b][:]
__global__ void k_prep(const float* __restrict__ WI, const float* __restrict__ vQ,
                       const float* __restrict__ WQ, const float* __restrict__ bQ,
                       u16* __restrict__ Wbf, float* __restrict__ qatt,
                       float* __restrict__ sums, float* __restrict__ u_raw) {
    const int blk = blockIdx.x, t = threadIdx.x;   // 128 threads
    if (blk < 64) {
        #pragma unroll
        for (int i = 0; i < 2; ++i) {
            int item = blk * 256 + i * 128 + t;    // 16384 items
            int a  = item & 127;
            int d0 = (item >> 7) << 2;
            ushort4 r;
            r.x = cvt_bf16(WI[(d0 + 0) * A_ + a]);
            r.y = cvt_bf16(WI[(d0 + 1) * A_ + a]);
            r.z = cvt_bf16(WI[(d0 + 2) * A_ + a]);
            r.w = cvt_bf16(WI[(d0 + 3) * A_ + a]);
            *(ushort4*)&Wbf[a * D_ + d0] = r;
        }
    } else {
        const int b = blk - 64;
        __shared__ float sq[D_];
        for (int d = t; d < D_; d += 128) sq[d] = vQ[b * D_ + d];
        __syncthreads();
        float acc = bQ[t];
        #pragma unroll 8
        for (int d = 0; d < D_; ++d) acc += sq[d] * WQ[d * A_ + t];
        qatt[b * A_ + t] = fast_tanh(acc);
        float4 z = {0.f, 0.f, 0.f, 0.f};
        *(float4*)(u_raw + b * D_ + t * 4) = z;
        if (t == 0) sums[b] = 0.0f;
    }
}

// ---------------------------------------------------------------- kernel 1
// Fused. Per block = 128 rows of batch b.
//  phase 1: m97-style DMA-staged MFMA GEMM (global_load_lds, 2-barrier K-loop)
//           -> logits -> w=exp(logit) -> wbuf + LDS, partial sum -> sums[b]
//  phase 2: re-read own 256 KB tile (L2/L3-hot), accumulate w.v_I -> u_raw
__global__ void __launch_bounds__(256)
k_fused(const float* __restrict__ vI, const u16* __restrict__ Wbf,
        const float* __restrict__ qatt, const float* __restrict__ Wp,
        float* __restrict__ wbuf, float* __restrict__ sums,
        float* __restrict__ u_raw) {
    const int b  = blockIdx.y;
    const int n0 = blockIdx.x * 128;
    const int t    = threadIdx.x;
    const int lane = t & 63, wave = t >> 6;
    const int l15  = lane & 15, quad = lane >> 4;

    __shared__ float sA[128 * BK];     // 32 KB, [row][k] fp32, 256 B/row (DMA: no pad)
    __shared__ u16   sB[128 * BK];     // 16 KB, [a][k] bf16, 128 B/row
    __shared__ float sw[128];
    __shared__ float wred[4];

    f32x4 acc[2][8];
    #pragma unroll
    for (int mt = 0; mt < 2; ++mt)
        #pragma unroll
        for (int nt = 0; nt < 8; ++nt)
            acc[mt][nt] = (f32x4){0.f, 0.f, 0.f, 0.f};

    const float* ga = vI + (size_t)(b * N_ + n0) * D_;

    // A staging: 8 calls/wave, call c: rows wave*32+c*4 .. +3 (4 x 256 B segs)
    const int a_row  = wave * 32 + (lane >> 4);        // +c*4
    const float* a_g = ga + (size_t)a_row * D_ + (lane & 15) * 4;
    float* a_l       = sA + (wave * 32) * BK;          // + c*4*BK (uniform)
    // B staging: 4 calls/wave, call c: a-rows wave*32+c*8 .. +7 (8 x 128 B segs)
    const int b_row  = wave * 32 + (lane >> 3);        // +c*8
    const u16* b_g   = Wbf + (size_t)b_row * D_ + (lane & 7) * 8;
    u16* b_l         = sB + (wave * 32) * BK;          // + c*8*BK (uniform)

    for (int kr = 0; kr < 8; ++kr) {
        const int k0 = kr * BK;
        #pragma unroll
        for (int c = 0; c < 8; ++c)
            gl_lds16(a_g + c * 4 * D_ + k0, a_l + c * 4 * BK);
        #pragma unroll
        for (int c = 0; c < 4; ++c)
            gl_lds16(b_g + c * 8 * D_ + k0, b_l + c * 8 * BK);
        __syncthreads();
        #pragma unroll
        for (int ks = 0; ks < 2; ++ks) {
            // A fragments: fp32 from LDS, pack to bf16
            bf16x8 af[2];
            #pragma unroll
            for (int mt = 0; mt < 2; ++mt) {
                const float* ap = sA + (wave * 32 + mt * 16 + l15) * BK + ks * 32 + quad * 8;
                float4 xa = *(const float4*)ap;
                float4 xb = *(const float4*)(ap + 4);
                union { bf16x8 v; unsigned u[4]; } cv;
                cv.u[0] = pack2_bf16(xa.x, xa.y);
                cv.u[1] = pack2_bf16(xa.z, xa.w);
                cv.u[2] = pack2_bf16(xb.x, xb.y);
                cv.u[3] = pack2_bf16(xb.z, xb.w);
                af[mt] = cv.v;
            }
            bf16x8 bfr[8];
            #pragma unroll
            for (int nt = 0; nt < 8; ++nt)
                bfr[nt] = *(const bf16x8*)(sB + (nt * 16 + l15) * BK + ks * 32 + quad * 8);
            #pragma unroll
            for (int mt = 0; mt < 2; ++mt)
                #pragma unroll
                for (int nt = 0; nt < 8; ++nt)
                    acc[mt][nt] = __builtin_amdgcn_mfma_f32_16x16x32_bf16(
                        af[mt], bfr[nt], acc[mt][nt], 0, 0, 0);
        }
        __syncthreads();
    }

    // epilogue: C/D layout col(a) = lane&15, row = quad*4 + reg
    float qa_v[8], wp_v[8];
    #pragma unroll
    for (int nt = 0; nt < 8; ++nt) {
        int a = nt * 16 + l15;
        qa_v[nt] = qatt[b * A_ + a];
        wp_v[nt] = Wp[a];
    }
    float lsum = 0.f;
    #pragma unroll
    for (int mt = 0; mt < 2; ++mt) {
        #pragma unroll
        for (int r = 0; r < 4; ++r) {
            float s = 0.f;
            #pragma unroll
            for (int nt = 0; nt < 8; ++nt) {
                float t1 = fast_tanh(acc[mt][nt][r]);
                float h  = fast_tanh(t1 + qa_v[nt]);
                s += h * wp_v[nt];
            }
            s += __shfl_xor(s, 1, 16);
            s += __shfl_xor(s, 2, 16);
            s += __shfl_xor(s, 4, 16);
            s += __shfl_xor(s, 8, 16);
            // |s| <= sum|W_p| ~ 9 -> exp safe in fp32; softmax needs no max-sub
            float we = __expf(s);
            lsum += we;                          // same value on all 16 lanes
            if (l15 == 0) {
                int rloc = wave * 32 + mt * 16 + quad * 4 + r;
                wbuf[(size_t)b * N_ + n0 + rloc] = we;
                sw[rloc] = we;
            }
        }
    }
    lsum += __shfl_xor(lsum, 16, 64);
    lsum += __shfl_xor(lsum, 32, 64);
    if (lane == 0) wred[wave] = lsum;
    __syncthreads();
    if (t == 0) atomicAdd(sums + b, wred[0] + wred[1] + wred[2] + wred[3]);

    // ---- phase 2: weighted sum of own tile (cache-hot re-read) ----
    const int rr = t >> 7;            // 0..1: two rows in flight
    const int c  = t & 127;           // float4 column
    const float4* base = (const float4*)(vI + (size_t)(b * N_ + n0 + rr) * D_) + c;
    float a0 = 0.f, a1 = 0.f, a2 = 0.f, a3 = 0.f;
    #pragma unroll 8
    for (int n = 0; n < 128; n += 2) {
        float4 x = base[n * 128];
        float wn = sw[n + rr];
        a0 += wn * x.x; a1 += wn * x.y; a2 += wn * x.z; a3 += wn * x.w;
    }
    float* ub = u_raw + b * D_ + c * 4;
    atomicAdd(ub + 0, a0);
    atomicAdd(ub + 1, a1);
    atomicAdd(ub + 2, a2);
    atomicAdd(ub + 3, a3);
}

// ---------------------------------------------------------------- kernel 2
// p[b][n] = w[b][n]/S_b ;  u[b][d] = u_raw[b][d]/S_b + v_Q[b][d]
__global__ void __launch_bounds__(256)
k_fin(const float* __restrict__ wbuf, const float* __restrict__ sums,
      const float* __restrict__ u_raw, const float* __restrict__ vQ,
      float* __restrict__ p_out, float* __restrict__ u_out) {
    const int b = blockIdx.x, t = threadIdx.x;    // 256 threads
    const float inv = 1.0f / sums[b];
    #pragma unroll
    for (int i = 0; i < 4; ++i) {
        float4 x = *(const float4*)(wbuf + (size_t)b * N_ + i * 1024 + t * 4);
        float4 y = { x.x * inv, x.y * inv, x.z * inv, x.w * inv };
        *(float4*)(p_out + (size_t)b * N_ + i * 1024 + t * 4) = y;
    }
    if (t < 128) {
        float4 ur = *(const float4*)(u_raw + b * D_ + t * 4);
        float4 vq = *(const float4*)(vQ + b * D_ + t * 4);
        float4 o  = { ur.x * inv + vq.x, ur.y * inv + vq.y,
                      ur.z * inv + vq.z, ur.w * inv + vq.w };
        *(float4*)(u_out + b * D_ + t * 4) = o;
    }
}

// ----------------------------------------------------------------
extern "C" void kernel_launch(void* const* d_in, const int* in_sizes, int n_in,
                              void* d_out, int out_size, void* d_ws, size_t ws_size,
                              hipStream_t stream) {
    const float* vI = (const float*)d_in[0];
    const float* vQ = (const float*)d_in[1];
    const float* WI = (const float*)d_in[2];
    const float* WQ = (const float*)d_in[3];
    const float* bQ = (const float*)d_in[4];
    const float* Wp = (const float*)d_in[5];
    // d_in[6] (b_p): constant added to all logits -> cancels in softmax.

    float* out_p = (float*)d_out;                    // [B][N]
    float* out_u = out_p + (size_t)B_ * N_;          // [B][D]

    char* ws = (char*)d_ws;
    u16*   Wbf   = (u16*)ws;                             // 128 KiB @ 0
    float* qatt  = (float*)(ws + 131072);                // 32 KiB
    float* sums  = (float*)(ws + 163840);                // 1 KiB
    float* u_raw = (float*)(ws + 164864);                // 128 KiB
    float* wbuf  = (float*)(ws + 295936);                // 1 MiB

    k_prep<<<128, 128, 0, stream>>>(WI, vQ, WQ, bQ, Wbf, qatt, sums, u_raw);
    k_fused<<<dim3(N_ / 128, B_), 256, 0, stream>>>(vI, Wbf, qatt, Wp,
                                                    wbuf, sums, u_raw);
    k_fin<<<B_, 256, 0, stream>>>(wbuf, sums, u_raw, vQ, out_p, out_u);
}